// Round 11
// baseline (261.338 us; speedup 1.0000x reference)
//
#include <hip/hip_runtime.h>
#include <stdint.h>

typedef __attribute__((ext_vector_type(4))) float f32x4;
typedef __attribute__((ext_vector_type(8))) short short8;
typedef unsigned short u16;
typedef unsigned int u32;
typedef unsigned long long u64;

#define GLDS16(g, l) __builtin_amdgcn_global_load_lds( \
    (const __attribute__((address_space(1))) void*)(g), \
    (__attribute__((address_space(3))) void*)(l), 16, 0, 0)

// compiler-level ordering fence (no instruction emitted): pins program order
// of memory ops so counted s_waitcnt vmcnt(N) arithmetic stays valid
#define ORDER_FENCE() asm volatile("" ::: "memory")

#if __has_builtin(__builtin_amdgcn_exp2f)
#define EXP2(x) __builtin_amdgcn_exp2f(x)
#else
#define EXP2(x) __expf(0.69314718056f * (x))
#endif

__device__ __forceinline__ u16 f2bf(float x) {
  u32 u = __float_as_uint(x);
  u += 0x7fffu + ((u >> 16) & 1u);
  return (u16)(u >> 16);
}

// ---------- prep: fp32->bf16 conversions + mask bit-pack ----------
__global__ __launch_bounds__(256) void prep_kernel(
    const float* __restrict__ q, const float* __restrict__ k,
    const float* __restrict__ v, const int* __restrict__ mask,
    const float* __restrict__ Wq, const float* __restrict__ Wk,
    const float* __restrict__ Wv, const float* __restrict__ Wo,
    u16* __restrict__ X, u16* __restrict__ Wb, u64* __restrict__ mb)
{
  const size_t tid = (size_t)blockIdx.x * 256 + threadIdx.x;
  const size_t nth = (size_t)gridDim.x * 256;
  for (size_t i = tid; i < 3ull * 524288ull; i += nth) {
    const int a = (int)(i / 524288ull);
    const size_t j = i - (size_t)a * 524288ull;
    const float4* s4 = (const float4*)(a == 0 ? q : a == 1 ? k : v);
    float4 x = s4[2 * j], y = s4[2 * j + 1];
    uint4 o;
    o.x = (u32)f2bf(x.x) | ((u32)f2bf(x.y) << 16);
    o.y = (u32)f2bf(x.z) | ((u32)f2bf(x.w) << 16);
    o.z = (u32)f2bf(y.x) | ((u32)f2bf(y.y) << 16);
    o.w = (u32)f2bf(y.z) | ((u32)f2bf(y.w) << 16);
    ((uint4*)X)[i] = o;
  }
  for (size_t i = tid; i < 4ull * 131072ull; i += nth) {
    const int a = (int)(i / 131072ull);
    const size_t j = i - (size_t)a * 131072ull;
    const float4* s4 = (const float4*)(a == 0 ? Wq : a == 1 ? Wk : a == 2 ? Wv : Wo);
    float4 x = s4[2 * j], y = s4[2 * j + 1];
    uint4 o;
    o.x = (u32)f2bf(x.x) | ((u32)f2bf(x.y) << 16);
    o.y = (u32)f2bf(x.z) | ((u32)f2bf(x.w) << 16);
    o.z = (u32)f2bf(y.x) | ((u32)f2bf(y.y) << 16);
    o.w = (u32)f2bf(y.z) | ((u32)f2bf(y.w) << 16);
    ((uint4*)Wb)[i] = o;
  }
  const int lane = threadIdx.x & 63;
  const size_t wid = tid >> 6, nw = nth >> 6;
  for (size_t wi = wid; wi < 131072ull; wi += nw) {
    int mm = mask[wi * 64 + lane];
    u64 bal = __ballot(mm != 0);
    if (lane == 0) mb[wi] = bal;
  }
}

// ---------- QKV projection GEMM: 128x128 tile, BK=64, NT bf16 ----------
// 1D grid (768) with XCD swizzle: each XCD owns 12 complete m-groups so all 8
// n-tiles sharing an A-panel are L2-co-located.
__global__ __launch_bounds__(256, 2) void gemm_qkv_kernel(
    const u16* __restrict__ X, const u16* __restrict__ W,
    const float* __restrict__ bq, const float* __restrict__ bk,
    const float* __restrict__ bv,
    u16* __restrict__ Qb, u16* __restrict__ Kb, u16* __restrict__ Vt)
{
  const int lid = blockIdx.x;
  const int g = (lid & 7) * 96 + (lid >> 3);   // bijective, 768 % 8 == 0
  const int z = g >> 8;
  const int rem = g & 255;
  const int m0 = (rem >> 3) * 128, n0 = (rem & 7) * 128;
  const char* A = (const char*)(X + (size_t)z * 4194304ull);
  const char* B = (const char*)(W + (size_t)z * 1048576ull);
  const float* bias = (z == 0) ? bq : (z == 1) ? bk : bv;
  const int tid = threadIdx.x, l = tid & 63, w = tid >> 6;
  const int wm = w >> 1, wn = w & 1;
  __shared__ __attribute__((aligned(16))) char SM[32768];
  char* Asm = SM;
  char* Bsm = SM + 16384;
  f32x4 acc[4][4] = {};
  for (int kt = 0; kt < 16; ++kt) {
#pragma unroll
    for (int j = 0; j < 4; ++j) {
      const int rt = w * 32 + j * 8 + (l >> 3);
      const int swk = ((l & 7) * 16) ^ ((rt & 7) << 4);
      GLDS16(A + (size_t)(m0 + rt) * 2048 + kt * 128 + swk, Asm + (w * 32 + j * 8) * 128);
      GLDS16(B + (size_t)(n0 + rt) * 2048 + kt * 128 + swk, Bsm + (w * 32 + j * 8) * 128);
    }
    __syncthreads();
#pragma unroll
    for (int kk = 0; kk < 2; ++kk) {
      short8 af[4], bfr[4];
#pragma unroll
      for (int mf = 0; mf < 4; ++mf) {
        const int row = wm * 64 + mf * 16 + (l & 15);
        const int kb = kk * 64 + (l >> 4) * 16;
        af[mf] = *(const short8*)(Asm + row * 128 + (kb ^ ((row & 7) << 4)));
      }
#pragma unroll
      for (int fc = 0; fc < 4; ++fc) {
        const int row = wn * 64 + fc * 16 + (l & 15);
        const int kb = kk * 64 + (l >> 4) * 16;
        bfr[fc] = *(const short8*)(Bsm + row * 128 + (kb ^ ((row & 7) << 4)));
      }
#pragma unroll
      for (int mf = 0; mf < 4; ++mf)
#pragma unroll
        for (int fc = 0; fc < 4; ++fc)
          acc[mf][fc] = __builtin_amdgcn_mfma_f32_16x16x32_bf16(af[mf], bfr[fc], acc[mf][fc], 0, 0, 0);
    }
    __syncthreads();
  }
  if (z < 2) {
    // fold 1/sqrt(64) * log2(e) into Q (attention runs in exp2 domain)
    const float scale = (z == 0) ? 0.18033688011f : 1.0f;
    u16* dst = (z == 0) ? Qb : Kb;
#pragma unroll
    for (int mf = 0; mf < 4; ++mf)
#pragma unroll
      for (int fc = 0; fc < 4; ++fc)
#pragma unroll
        for (int r = 0; r < 4; ++r) {
          const int m = m0 + wm * 64 + mf * 16 + (l >> 4) * 4 + r;
          const int n = n0 + wn * 64 + fc * 16 + (l & 15);
          const float val = (acc[mf][fc][r] + bias[n]) * scale;
          const int bb = m >> 11, s = m & 2047;
          const int hh = n >> 6, dd = n & 63;
          dst[((size_t)(bb * 16 + hh) * 2048 + s) * 64 + dd] = f2bf(val);
        }
  } else {
    // transpose tile through LDS for coalesced Vt ([bh][d][s]) stores
#pragma unroll
    for (int mf = 0; mf < 4; ++mf)
#pragma unroll
      for (int fc = 0; fc < 4; ++fc)
#pragma unroll
        for (int r = 0; r < 4; ++r) {
          const int n_l = wn * 64 + fc * 16 + (l & 15);
          const int m_l = wm * 64 + mf * 16 + (l >> 4) * 4 + r;
          const float val = acc[mf][fc][r] + bias[n0 + n_l];
          *(u16*)(SM + n_l * 256 + ((m_l * 2) ^ ((n_l & 15) << 4))) = f2bf(val);
        }
    __syncthreads();
    const int bb = m0 >> 11, ms = m0 & 2047;
#pragma unroll
    for (int rep = 0; rep < 8; ++rep) {
      const int n_l = rep * 16 + (tid >> 4);
      const int m8 = (tid & 15) * 8;
      const uint4 dv = *(const uint4*)(SM + n_l * 256 + ((m8 * 2) ^ ((n_l & 15) << 4)));
      const int hh = (n0 + n_l) >> 6, dd = (n0 + n_l) & 63;
      *(uint4*)(Vt + ((size_t)((bb * 16 + hh) * 64 + dd)) * 2048 + ms + m8) = dv;
    }
  }
}

// ---------- lsum: l[bh][q] = sum_k keep * exp2(q.k) ----------
// Mirrors attn's QK phase exactly: QBLK=128, BK=64 (32 tiles), 512 threads,
// wave split (wk = k-frag, wqh = q-half), counted vmcnt + reg mask prefetch.
// 1D grid (512) with XCD swizzle: 4 bh per XCD (K L2-local).
__global__ __launch_bounds__(512, 4) void lsum_kernel(
    const u16* __restrict__ Qb, const u16* __restrict__ Kb,
    const u32* __restrict__ mbits, float* __restrict__ lrow)
{
  const int lid = blockIdx.x;
  const int swz = (lid & 7) * 64 + (lid >> 3);   // bijective (512 % 8 == 0)
  const int bh = swz >> 4, qb = swz & 15;
  const int b = bh >> 4;
  const int q0 = qb * 128;
  const int tid = threadIdx.x, l = tid & 63, w = tid >> 6;
  const int wk = w & 3, wqh = w >> 2;

  __shared__ __attribute__((aligned(16))) char kbuf[2][8192];
  __shared__ __attribute__((aligned(16))) char Qsm[16384];
  __shared__ float rbuf[8][64];

  const char* Qrow = (const char*)(Qb + (size_t)bh * 131072ull);
  const char* Krow = (const char*)(Kb + (size_t)bh * 131072ull);

  // prologue: stage Q (to Qsm), K(0)
  {
    const int row = tid >> 3, byte = (tid & 7) * 16;
    GLDS16(Qrow + (size_t)(q0 + row) * 128 + (byte ^ ((row & 7) << 4)), Qsm + w * 1024);
    const int row2 = 64 + row;
    GLDS16(Qrow + (size_t)(q0 + row2) * 128 + (byte ^ ((row2 & 7) << 4)), Qsm + 8192 + w * 1024);
    GLDS16(Krow + (size_t)row * 128 + (byte ^ ((row & 7) << 4)), kbuf[0] + w * 1024);
  }
  __syncthreads();
  short8 aq[4][2];
#pragma unroll
  for (int qf = 0; qf < 4; ++qf)
#pragma unroll
    for (int kk = 0; kk < 2; ++kk) {
      const int row = wqh * 64 + qf * 16 + (l & 15);
      aq[qf][kk] = *(const short8*)(Qsm + row * 128 +
                                    ((kk * 64 + (l >> 4) * 16) ^ ((row & 7) << 4)));
    }

  // per-qf mask row pointers (word column fixed = wk>>1)
  const u32* mbase[4];
#pragma unroll
  for (int qf = 0; qf < 4; ++qf)
    mbase[qf] = mbits + (size_t)(b * 2048 + q0 + wqh * 64 + qf * 16 + (l & 15)) * 64 + (wk >> 1);
  ORDER_FENCE();
  u32 mreg[4];
#pragma unroll
  for (int qf = 0; qf < 4; ++qf) mreg[qf] = mbase[qf][0];

  float lsum[4] = {0.f, 0.f, 0.f, 0.f};
  const int kbit = (wk & 1) * 16 + (l >> 4) * 4;
  for (int t = 0; t < 32; ++t) {
    // own K(t) glds retired (4 mask loads, newer, stay in flight); barrier
    // makes all threads' staging visible (t=0 covered: prologue glds is oldest)
    asm volatile("s_waitcnt vmcnt(4) lgkmcnt(0)" ::: "memory");
    __builtin_amdgcn_s_barrier();
    u32 mnext[4] = {0, 0, 0, 0};
    if (t < 31) {
      const int row = tid >> 3, byte = (tid & 7) * 16;
      ORDER_FENCE();
      GLDS16(Krow + (size_t)((t + 1) * 64 + row) * 128 + (byte ^ ((row & 7) << 4)),
             kbuf[(t + 1) & 1] + w * 1024);
      ORDER_FENCE();
#pragma unroll
      for (int qf = 0; qf < 4; ++qf) mnext[qf] = mbase[qf][(t + 1) * 2];
      ORDER_FENCE();
    }
    short8 ak[2];
    {
      const int krow = wk * 16 + (l & 15);
      ak[0] = *(const short8*)(kbuf[t & 1] + krow * 128 +
                               (((l >> 4) * 16) ^ ((krow & 7) << 4)));
      ak[1] = *(const short8*)(kbuf[t & 1] + krow * 128 +
                               ((64 + (l >> 4) * 16) ^ ((krow & 7) << 4)));
    }
#pragma unroll
    for (int qf = 0; qf < 4; ++qf) {
      f32x4 sc = {0.f, 0.f, 0.f, 0.f};
      sc = __builtin_amdgcn_mfma_f32_16x16x32_bf16(ak[0], aq[qf][0], sc, 0, 0, 0);
      sc = __builtin_amdgcn_mfma_f32_16x16x32_bf16(ak[1], aq[qf][1], sc, 0, 0, 0);
      float s = 0.f;
#pragma unroll
      for (int r = 0; r < 4; ++r)
        s += ((mreg[qf] >> (kbit + r)) & 1u) ? 0.f : EXP2(sc[r]);
      lsum[qf] += s;
    }
#pragma unroll
    for (int qf = 0; qf < 4; ++qf) mreg[qf] = mnext[qf];
  }
  // reduce: xor over l>>4 (the wave's 16-k slice), then LDS over the 4 wk-waves
#pragma unroll
  for (int qf = 0; qf < 4; ++qf) {
    float v = lsum[qf];
    v += __shfl_xor(v, 16);
    v += __shfl_xor(v, 32);
    if (l < 16) rbuf[w][qf * 16 + l] = v;   // w = wqh*4 + wk
  }
  __syncthreads();
  if (tid < 128) {
    const int half = tid >> 6, qi = tid & 63;
    lrow[(size_t)bh * 2048 + q0 + tid] =
        rbuf[half * 4 + 0][qi] + rbuf[half * 4 + 1][qi] +
        rbuf[half * 4 + 2][qi] + rbuf[half * 4 + 3][qi];
  }
}

// ---------- single-pass fused attention, single-barrier deferred-PV pipeline ----
// QBLK=128, BK=64 (32 tiles), 512 threads. Per tile: one barrier; stores+PV of
// tile t-1 run after it (P double-buffered, V triple-buffered).
// Grid flattened to 512 with XCD swizzle: 4 consecutive bh per XCD (K/V L2-local).
__global__ __launch_bounds__(512, 4) void attn_kernel(
    const u16* __restrict__ Qb, const u16* __restrict__ Kb,
    const u16* __restrict__ Vt, const u32* __restrict__ mbits,
    const float* __restrict__ lrow, float* __restrict__ attn,
    u16* __restrict__ preWo)
{
  const int lid = blockIdx.x;
  const int swz = (lid & 7) * 64 + (lid >> 3);   // bijective (512 % 8 == 0)
  const int bh = swz >> 4, qb = swz & 15;
  const int b = bh >> 4, h = bh & 15;
  const int q0 = qb * 128;
  const int tid = threadIdx.x, l = tid & 63, w = tid >> 6;
  const int wk = w & 3, wqh = w >> 2;   // QK phase: k-frag, q-half
  const int wq = w >> 1, wd = w & 1;    // PV phase: q-quarter, d-half

  __shared__ __attribute__((aligned(16))) char kbuf[2][8192];
  __shared__ __attribute__((aligned(16))) char vbuf[3][8192];
  __shared__ __attribute__((aligned(16))) char Psm[2][16384];  // P bf16 [128][64] x2

  const char* Qrow = (const char*)(Qb + (size_t)bh * 131072ull);
  const char* Krow = (const char*)(Kb + (size_t)bh * 131072ull);
  const char* Vrow = (const char*)(Vt + (size_t)bh * 131072ull);

  // prologue: stage Q (into Psm[0] temporarily), K(0), V(0)
  {
    const int row = tid >> 3, byte = (tid & 7) * 16;
    GLDS16(Qrow + (size_t)(q0 + row) * 128 + (byte ^ ((row & 7) << 4)), Psm[0] + w * 1024);
    const int row2 = 64 + row;
    GLDS16(Qrow + (size_t)(q0 + row2) * 128 + (byte ^ ((row2 & 7) << 4)), Psm[0] + 8192 + w * 1024);
    GLDS16(Krow + (size_t)row * 128 + (byte ^ ((row & 7) << 4)), kbuf[0] + w * 1024);
    GLDS16(Vrow + (size_t)row * 4096 + (byte ^ ((row & 7) << 4)), vbuf[0] + w * 1024);
  }
  __syncthreads();
  short8 aq[4][2];
#pragma unroll
  for (int qf = 0; qf < 4; ++qf)
#pragma unroll
    for (int kk = 0; kk < 2; ++kk) {
      const int row = wqh * 64 + qf * 16 + (l & 15);
      aq[qf][kk] = *(const short8*)(Psm[0] + row * 128 +
                                    ((kk * 64 + (l >> 4) * 16) ^ ((row & 7) << 4)));
    }
  float il[4];
#pragma unroll
  for (int qf = 0; qf < 4; ++qf) {
    const float lv = lrow[(size_t)bh * 2048 + q0 + wqh * 64 + qf * 16 + (l & 15)];
    il[qf] = (lv > 0.f) ? 1.0f / lv : 0.f;
  }
  __syncthreads();   // Q frag reads done; Psm[0] free for P(0)

  // per-qf mask row pointers (word column fixed = wk>>1)
  const u32* mbase[4];
#pragma unroll
  for (int qf = 0; qf < 4; ++qf)
    mbase[qf] = mbits + (size_t)(b * 2048 + q0 + wqh * 64 + qf * 16 + (l & 15)) * 64 + (wk >> 1);
  u32 mreg[4];
#pragma unroll
  for (int qf = 0; qf < 4; ++qf) mreg[qf] = mbase[qf][0];

  f32x4 oacc[2][2] = {};
  const int kbit = (wk & 1) * 16 + (l >> 4) * 4;
  int vstage = 1, vprev = 2;   // (t+1)%3 and (t-1)%3 ring indices
  for (int t = 0; t < 32; ++t) {
    // single barrier per tile: staging(t) visible + P(t-1) visible.
    // vmcnt: in-order retirement; ops newer than staging(t) = 4 mask (+4 stores
    // once t>=2) -> vmcnt(4) at t==1, vmcnt(8) after. t==0 covered by prologue.
    if (t == 1) {
      asm volatile("s_waitcnt vmcnt(4) lgkmcnt(0)" ::: "memory");
      __builtin_amdgcn_s_barrier();
    } else if (t >= 2) {
      asm volatile("s_waitcnt vmcnt(8) lgkmcnt(0)" ::: "memory");
      __builtin_amdgcn_s_barrier();
    }
    u32 mnext[4] = {0, 0, 0, 0};
    if (t < 31) {
      const int row = tid >> 3, byte = (tid & 7) * 16;
      ORDER_FENCE();
      GLDS16(Krow + (size_t)((t + 1) * 64 + row) * 128 + (byte ^ ((row & 7) << 4)),
             kbuf[(t + 1) & 1] + w * 1024);
      GLDS16(Vrow + (size_t)row * 4096 + (t + 1) * 128 + (byte ^ ((row & 7) << 4)),
             vbuf[vstage] + w * 1024);
      ORDER_FENCE();
#pragma unroll
      for (int qf = 0; qf < 4; ++qf) mnext[qf] = mbase[qf][(t + 1) * 2];
      ORDER_FENCE();
    }
    // deferred attn stores for tile t-1 (coalesced 256B readback from Psm)
    if (t > 0) {
      const char* Pp = Psm[(t - 1) & 1];
#pragma unroll
      for (int it = 0; it < 4; ++it) {
        const int q = w * 16 + it * 4 + (l >> 4);
        const uint2 pv = *(const uint2*)(Pp + q * 128 + (((l & 15) * 8) ^ ((q & 7) << 4)));
        f32x4 o;
        o[0] = __uint_as_float(pv.x << 16);
        o[1] = __uint_as_float(pv.x & 0xffff0000u);
        o[2] = __uint_as_float(pv.y << 16);
        o[3] = __uint_as_float(pv.y & 0xffff0000u);
        __builtin_nontemporal_store(o, (f32x4*)(attn +
            ((size_t)bh * 2048 + q0 + q) * 2048 + (t - 1) * 64 + (l & 15) * 4));
      }
    }
    // QK(t) (swapped operands): sc rows = k-local, cols = q-local
    short8 ak[2];
    {
      const int krow = wk * 16 + (l & 15);
      ak[0] = *(const short8*)(kbuf[t & 1] + krow * 128 +
                               (((l >> 4) * 16) ^ ((krow & 7) << 4)));
      ak[1] = *(const short8*)(kbuf[t & 1] + krow * 128 +
                               ((64 + (l >> 4) * 16) ^ ((krow & 7) << 4)));
    }
#pragma unroll
    for (int qf = 0; qf < 4; ++qf) {
      f32x4 sc = {0.f, 0.f, 0.f, 0.f};
      sc = __builtin_amdgcn_mfma_f32_16x16x32_bf16(ak[0], aq[qf][0], sc, 0, 0, 0);
      sc = __builtin_amdgcn_mfma_f32_16x16x32_bf16(ak[1], aq[qf][1], sc, 0, 0, 0);
      const int q = wqh * 64 + qf * 16 + (l & 15);
      float p[4];
#pragma unroll
      for (int r = 0; r < 4; ++r)
        p[r] = ((mreg[qf] >> (kbit + r)) & 1u) ? 0.f : EXP2(sc[r]) * il[qf];
      uint2 pk;
      pk.x = (u32)f2bf(p[0]) | ((u32)f2bf(p[1]) << 16);
      pk.y = (u32)f2bf(p[2]) | ((u32)f2bf(p[3]) << 16);
      *(uint2*)(Psm[t & 1] + q * 128 + ((wk * 32 + (l >> 4) * 8) ^ ((q & 7) << 4))) = pk;
    }
#pragma unroll
    for (int qf = 0; qf < 4; ++qf) mreg[qf] = mnext[qf];
    // PV(t-1): oacc += P(t-1) x V(t-1)
    if (t > 0) {
      const char* Pp = Psm[(t - 1) & 1];
#pragma unroll
      for (int ka = 0; ka < 2; ++ka) {
        short8 pa[2], vb[2];
#pragma unroll
        for (int i = 0; i < 2; ++i) {
          const int qr = wq * 32 + i * 16 + (l & 15);
          pa[i] = *(const short8*)(Pp + qr * 128 +
                                   ((ka * 64 + (l >> 4) * 16) ^ ((qr & 7) << 4)));
        }
#pragma unroll
        for (int j = 0; j < 2; ++j) {
          const int dr = wd * 32 + j * 16 + (l & 15);
          vb[j] = *(const short8*)(vbuf[vprev] + dr * 128 +
                                   ((ka * 64 + (l >> 4) * 16) ^ ((dr & 7) << 4)));
        }
#pragma unroll
        for (int i = 0; i < 2; ++i)
#pragma unroll
          for (int j = 0; j < 2; ++j)
            oacc[i][j] = __builtin_amdgcn_mfma_f32_16x16x32_bf16(pa[i], vb[j], oacc[i][j], 0, 0, 0);
      }
    }
    vstage = (vstage == 2) ? 0 : vstage + 1;
    vprev = (vprev == 2) ? 0 : vprev + 1;
  }

  // tail: stores(31) + PV(31); V(31) lives in vbuf[31 % 3 = 1]
  asm volatile("s_waitcnt lgkmcnt(0)" ::: "memory");
  __builtin_amdgcn_s_barrier();
  {
    const char* Pp = Psm[1];
#pragma unroll
    for (int it = 0; it < 4; ++it) {
      const int q = w * 16 + it * 4 + (l >> 4);
      const uint2 pv = *(const uint2*)(Pp + q * 128 + (((l & 15) * 8) ^ ((q & 7) << 4)));
      f32x4 o;
      o[0] = __uint_as_float(pv.x << 16);
      o[1] = __uint_as_float(pv.x & 0xffff0000u);
      o[2] = __uint_as_float(pv.y << 16);
      o[3] = __uint_as_float(pv.y & 0xffff0000u);
      __builtin_nontemporal_store(o, (f32x4*)(attn +
          ((size_t)bh * 2048 + q0 + q) * 2048 + 31 * 64 + (l & 15) * 4));
    }
#pragma unroll
    for (int ka = 0; ka < 2; ++ka) {
      short8 pa[2], vb[2];
#pragma unroll
      for (int i = 0; i < 2; ++i) {
        const int qr = wq * 32 + i * 16 + (l & 15);
        pa[i] = *(const short8*)(Pp + qr * 128 +
                                 ((ka * 64 + (l >> 4) * 16) ^ ((qr & 7) << 4)));
      }
#pragma unroll
      for (int j = 0; j < 2; ++j) {
        const int dr = wd * 32 + j * 16 + (l & 15);
        vb[j] = *(const short8*)(vbuf[1] + dr * 128 +
                                 ((ka * 64 + (l >> 4) * 16) ^ ((dr & 7) << 4)));
      }
#pragma unroll
      for (int i = 0; i < 2; ++i)
#pragma unroll
        for (int j = 0; j < 2; ++j)
          oacc[i][j] = __builtin_amdgcn_mfma_f32_16x16x32_bf16(pa[i], vb[j], oacc[i][j], 0, 0, 0);
    }
  }

  // epilogue: O (already normalized) scattered into the buggy-reshape layout
#pragma unroll
  for (int i = 0; i < 2; ++i)
#pragma unroll
    for (int j = 0; j < 2; ++j)
#pragma unroll
      for (int r = 0; r < 4; ++r) {
        const int qg = q0 + wq * 32 + i * 16 + (l >> 4) * 4 + r;
        const int dd = wd * 32 + j * 16 + (l & 15);
        const size_t off = (size_t)b * 2097152ull +
                           ((size_t)((h >> 1) * 256 + (qg >> 3))) * 1024ull +
                           (size_t)((qg & 7) * 128 + (h & 1) * 64 + dd);
        preWo[off] = f2bf(oacc[i][j][r]);
      }
}

// ---------- output projection GEMM: 128x64 tiles, 1D grid (512), XCD swizzle ----
__global__ __launch_bounds__(256, 2) void gemm_out_kernel(
    const u16* __restrict__ A0, const u16* __restrict__ B0,
    const float* __restrict__ bias, float* __restrict__ out)
{
  const char* A = (const char*)A0;
  const char* B = (const char*)B0;
  const int lid = blockIdx.x;
  const int g = (lid & 7) * 64 + (lid >> 3);   // bijective, 512 % 8 == 0
  const int m0 = (g >> 4) * 128, n0 = (g & 15) * 64;
  const int tid = threadIdx.x, l = tid & 63, w = tid >> 6;
  const int wm = w >> 1, wn = w & 1;
  __shared__ __attribute__((aligned(16))) char SM[24576];
  char* Asm = SM;
  char* Bsm = SM + 16384;
  f32x4 acc[4][2] = {};
  for (int kt = 0; kt < 16; ++kt) {
#pragma unroll
    for (int j = 0; j < 4; ++j) {
      const int rt = w * 32 + j * 8 + (l >> 3);
      const int swk = ((l & 7) * 16) ^ ((rt & 7) << 4);
      GLDS16(A + (size_t)(m0 + rt) * 2048 + kt * 128 + swk, Asm + (w * 32 + j * 8) * 128);
    }
#pragma unroll
    for (int j = 0; j < 2; ++j) {
      const int rt = w * 16 + j * 8 + (l >> 3);
      const int swk = ((l & 7) * 16) ^ ((rt & 7) << 4);
      GLDS16(B + (size_t)(n0 + rt) * 2048 + kt * 128 + swk, Bsm + (w * 16 + j * 8) * 128);
    }
    __syncthreads();
#pragma unroll
    for (int kk = 0; kk < 2; ++kk) {
      short8 af[4], bfr[2];
#pragma unroll
      for (int mf = 0; mf < 4; ++mf) {
        const int row = wm * 64 + mf * 16 + (l & 15);
        const int kb = kk * 64 + (l >> 4) * 16;
        af[mf] = *(const short8*)(Asm + row * 128 + (kb ^ ((row & 7) << 4)));
      }
#pragma unroll
      for (int fc = 0; fc < 2; ++fc) {
        const int row = wn * 32 + fc * 16 + (l & 15);
        const int kb = kk * 64 + (l >> 4) * 16;
        bfr[fc] = *(const short8*)(Bsm + row * 128 + (kb ^ ((row & 7) << 4)));
      }
#pragma unroll
      for (int mf = 0; mf < 4; ++mf)
#pragma unroll
        for (int fc = 0; fc < 2; ++fc)
          acc[mf][fc] = __builtin_amdgcn_mfma_f32_16x16x32_bf16(af[mf], bfr[fc], acc[mf][fc], 0, 0, 0);
    }
    __syncthreads();
  }
#pragma unroll
  for (int mf = 0; mf < 4; ++mf)
#pragma unroll
    for (int fc = 0; fc < 2; ++fc)
#pragma unroll
      for (int r = 0; r < 4; ++r) {
        const int m = m0 + wm * 64 + mf * 16 + (l >> 4) * 4 + r;
        const int n = n0 + wn * 32 + fc * 16 + (l & 15);
        out[(size_t)m * 1024 + n] = acc[mf][fc][r] + bias[n];
      }
}

extern "C" void kernel_launch(void* const* d_in, const int* in_sizes, int n_in,
                              void* d_out, int out_size, void* d_ws, size_t ws_size,
                              hipStream_t stream) {
  const float* q  = (const float*)d_in[0];
  const float* k  = (const float*)d_in[1];
  const float* v  = (const float*)d_in[2];
  const int*  mask = (const int*)d_in[3];
  const float* Wq = (const float*)d_in[5];
  const float* bq = (const float*)d_in[6];
  const float* Wk = (const float*)d_in[7];
  const float* bk = (const float*)d_in[8];
  const float* Wv = (const float*)d_in[9];
  const float* bv = (const float*)d_in[10];
  const float* Wo = (const float*)d_in[11];
  const float* bo = (const float*)d_in[12];

  float* out0 = (float*)d_out;
  float* attn = out0 + 4194304;            // [32][2048][2048] fp32
  u16* X = (u16*)attn;                     // bf16 q,k,v staging lives in the attn
                                           // region until attn_kernel overwrites it
  char* ws = (char*)d_ws;
  u16* Qb    = (u16*)(ws);                 // [32][2048][64] bf16
  u16* Kb    = (u16*)(ws + 8388608);
  u16* Vt    = (u16*)(ws + 16777216);      // [32][64][2048] bf16
  u16* preWo = (u16*)(ws + 25165824);      // [4096][1024] bf16 (scrambled layout)
  u16* Wb    = (u16*)(ws + 33554432);      // Wq,Wk,Wv,Wo bf16
  u32* mbits = (u32*)(ws + 41943040);      // [2][2048][64] bit-packed mask
  // lrow reuses the Wq-bf16 slot (Wq only needed by gemm_qkv, which runs earlier)
  float* lrow = (float*)(ws + 33554432);   // [32][2048] fp32

  prep_kernel<<<dim3(1024), 256, 0, stream>>>(q, k, v, mask, Wq, Wk, Wv, Wo,
                                              X, Wb, (u64*)mbits);
  gemm_qkv_kernel<<<dim3(768), 256, 0, stream>>>(X, Wb, bq, bk, bv, Qb, Kb, Vt);
  lsum_kernel<<<dim3(512), 512, 0, stream>>>(Qb, Kb, mbits, lrow);
  attn_kernel<<<dim3(512), 512, 0, stream>>>(Qb, Kb, Vt, mbits, lrow, attn, preWo);
  gemm_out_kernel<<<dim3(512), 256, 0, stream>>>(preWo, Wb + 3u * 1048576u, bo, out0);
}

// Round 12
// 244.418 us; speedup vs baseline: 1.0692x; 1.0692x over previous
//
#include <hip/hip_runtime.h>
#include <stdint.h>

typedef __attribute__((ext_vector_type(4))) float f32x4;
typedef __attribute__((ext_vector_type(8))) short short8;
typedef unsigned short u16;
typedef unsigned int u32;
typedef unsigned long long u64;

#define GLDS16(g, l) __builtin_amdgcn_global_load_lds( \
    (const __attribute__((address_space(1))) void*)(g), \
    (__attribute__((address_space(3))) void*)(l), 16, 0, 0)

// compiler-level ordering fence (no instruction emitted): pins program order
// of memory ops so counted s_waitcnt vmcnt(N) arithmetic stays valid
#define ORDER_FENCE() asm volatile("" ::: "memory")

#if __has_builtin(__builtin_amdgcn_exp2f)
#define EXP2(x) __builtin_amdgcn_exp2f(x)
#else
#define EXP2(x) __expf(0.69314718056f * (x))
#endif

__device__ __forceinline__ u16 f2bf(float x) {
  u32 u = __float_as_uint(x);
  u += 0x7fffu + ((u >> 16) & 1u);
  return (u16)(u >> 16);
}

// ---------- prep: fp32->bf16 conversions + mask bit-pack ----------
__global__ __launch_bounds__(256) void prep_kernel(
    const float* __restrict__ q, const float* __restrict__ k,
    const float* __restrict__ v, const int* __restrict__ mask,
    const float* __restrict__ Wq, const float* __restrict__ Wk,
    const float* __restrict__ Wv, const float* __restrict__ Wo,
    u16* __restrict__ X, u16* __restrict__ Wb, u64* __restrict__ mb)
{
  const size_t tid = (size_t)blockIdx.x * 256 + threadIdx.x;
  const size_t nth = (size_t)gridDim.x * 256;
  for (size_t i = tid; i < 3ull * 524288ull; i += nth) {
    const int a = (int)(i / 524288ull);
    const size_t j = i - (size_t)a * 524288ull;
    const float4* s4 = (const float4*)(a == 0 ? q : a == 1 ? k : v);
    float4 x = s4[2 * j], y = s4[2 * j + 1];
    uint4 o;
    o.x = (u32)f2bf(x.x) | ((u32)f2bf(x.y) << 16);
    o.y = (u32)f2bf(x.z) | ((u32)f2bf(x.w) << 16);
    o.z = (u32)f2bf(y.x) | ((u32)f2bf(y.y) << 16);
    o.w = (u32)f2bf(y.z) | ((u32)f2bf(y.w) << 16);
    ((uint4*)X)[i] = o;
  }
  for (size_t i = tid; i < 4ull * 131072ull; i += nth) {
    const int a = (int)(i / 131072ull);
    const size_t j = i - (size_t)a * 131072ull;
    const float4* s4 = (const float4*)(a == 0 ? Wq : a == 1 ? Wk : a == 2 ? Wv : Wo);
    float4 x = s4[2 * j], y = s4[2 * j + 1];
    uint4 o;
    o.x = (u32)f2bf(x.x) | ((u32)f2bf(x.y) << 16);
    o.y = (u32)f2bf(x.z) | ((u32)f2bf(x.w) << 16);
    o.z = (u32)f2bf(y.x) | ((u32)f2bf(y.y) << 16);
    o.w = (u32)f2bf(y.z) | ((u32)f2bf(y.w) << 16);
    ((uint4*)Wb)[i] = o;
  }
  const int lane = threadIdx.x & 63;
  const size_t wid = tid >> 6, nw = nth >> 6;
  for (size_t wi = wid; wi < 131072ull; wi += nw) {
    int mm = mask[wi * 64 + lane];
    u64 bal = __ballot(mm != 0);
    if (lane == 0) mb[wi] = bal;
  }
}

// ---------- QKV projection GEMM: 128x128 tile, BK=64, NT bf16 ----------
// 1D grid (768) with XCD swizzle: each XCD owns 12 complete m-groups so all 8
// n-tiles sharing an A-panel are L2-co-located.
__global__ __launch_bounds__(256, 2) void gemm_qkv_kernel(
    const u16* __restrict__ X, const u16* __restrict__ W,
    const float* __restrict__ bq, const float* __restrict__ bk,
    const float* __restrict__ bv,
    u16* __restrict__ Qb, u16* __restrict__ Kb, u16* __restrict__ Vt)
{
  const int lid = blockIdx.x;
  const int g = (lid & 7) * 96 + (lid >> 3);   // bijective, 768 % 8 == 0
  const int z = g >> 8;
  const int rem = g & 255;
  const int m0 = (rem >> 3) * 128, n0 = (rem & 7) * 128;
  const char* A = (const char*)(X + (size_t)z * 4194304ull);
  const char* B = (const char*)(W + (size_t)z * 1048576ull);
  const float* bias = (z == 0) ? bq : (z == 1) ? bk : bv;
  const int tid = threadIdx.x, l = tid & 63, w = tid >> 6;
  const int wm = w >> 1, wn = w & 1;
  __shared__ __attribute__((aligned(16))) char SM[32768];
  char* Asm = SM;
  char* Bsm = SM + 16384;
  f32x4 acc[4][4] = {};
  for (int kt = 0; kt < 16; ++kt) {
#pragma unroll
    for (int j = 0; j < 4; ++j) {
      const int rt = w * 32 + j * 8 + (l >> 3);
      const int swk = ((l & 7) * 16) ^ ((rt & 7) << 4);
      GLDS16(A + (size_t)(m0 + rt) * 2048 + kt * 128 + swk, Asm + (w * 32 + j * 8) * 128);
      GLDS16(B + (size_t)(n0 + rt) * 2048 + kt * 128 + swk, Bsm + (w * 32 + j * 8) * 128);
    }
    __syncthreads();
#pragma unroll
    for (int kk = 0; kk < 2; ++kk) {
      short8 af[4], bfr[4];
#pragma unroll
      for (int mf = 0; mf < 4; ++mf) {
        const int row = wm * 64 + mf * 16 + (l & 15);
        const int kb = kk * 64 + (l >> 4) * 16;
        af[mf] = *(const short8*)(Asm + row * 128 + (kb ^ ((row & 7) << 4)));
      }
#pragma unroll
      for (int fc = 0; fc < 4; ++fc) {
        const int row = wn * 64 + fc * 16 + (l & 15);
        const int kb = kk * 64 + (l >> 4) * 16;
        bfr[fc] = *(const short8*)(Bsm + row * 128 + (kb ^ ((row & 7) << 4)));
      }
#pragma unroll
      for (int mf = 0; mf < 4; ++mf)
#pragma unroll
        for (int fc = 0; fc < 4; ++fc)
          acc[mf][fc] = __builtin_amdgcn_mfma_f32_16x16x32_bf16(af[mf], bfr[fc], acc[mf][fc], 0, 0, 0);
    }
    __syncthreads();
  }
  if (z < 2) {
    // fold 1/sqrt(64) * log2(e) into Q (attention runs in exp2 domain)
    const float scale = (z == 0) ? 0.18033688011f : 1.0f;
    u16* dst = (z == 0) ? Qb : Kb;
#pragma unroll
    for (int mf = 0; mf < 4; ++mf)
#pragma unroll
      for (int fc = 0; fc < 4; ++fc)
#pragma unroll
        for (int r = 0; r < 4; ++r) {
          const int m = m0 + wm * 64 + mf * 16 + (l >> 4) * 4 + r;
          const int n = n0 + wn * 64 + fc * 16 + (l & 15);
          const float val = (acc[mf][fc][r] + bias[n]) * scale;
          const int bb = m >> 11, s = m & 2047;
          const int hh = n >> 6, dd = n & 63;
          dst[((size_t)(bb * 16 + hh) * 2048 + s) * 64 + dd] = f2bf(val);
        }
  } else {
    // transpose tile through LDS for coalesced Vt ([bh][d][s]) stores
#pragma unroll
    for (int mf = 0; mf < 4; ++mf)
#pragma unroll
      for (int fc = 0; fc < 4; ++fc)
#pragma unroll
        for (int r = 0; r < 4; ++r) {
          const int n_l = wn * 64 + fc * 16 + (l & 15);
          const int m_l = wm * 64 + mf * 16 + (l >> 4) * 4 + r;
          const float val = acc[mf][fc][r] + bias[n0 + n_l];
          *(u16*)(SM + n_l * 256 + ((m_l * 2) ^ ((n_l & 15) << 4))) = f2bf(val);
        }
    __syncthreads();
    const int bb = m0 >> 11, ms = m0 & 2047;
#pragma unroll
    for (int rep = 0; rep < 8; ++rep) {
      const int n_l = rep * 16 + (tid >> 4);
      const int m8 = (tid & 15) * 8;
      const uint4 dv = *(const uint4*)(SM + n_l * 256 + ((m8 * 2) ^ ((n_l & 15) << 4)));
      const int hh = (n0 + n_l) >> 6, dd = (n0 + n_l) & 63;
      *(uint4*)(Vt + ((size_t)((bb * 16 + hh) * 64 + dd)) * 2048 + ms + m8) = dv;
    }
  }
}

// ---------- lsum: l[bh][q] = sum_k keep * exp2(q.k) ----------
// QBLK=64, BK=128, 256 threads. 1D grid (1024) with XCD swizzle: 4 bh per XCD.
__global__ __launch_bounds__(256, 4) void lsum_kernel(
    const u16* __restrict__ Qb, const u16* __restrict__ Kb,
    const u32* __restrict__ mbits, float* __restrict__ lrow)
{
  const int lid = blockIdx.x;
  const int g = (lid & 7) * 128 + (lid >> 3);  // bijective, 1024 % 8 == 0
  const int bh = g >> 5, qb = g & 31;
  const int b = bh >> 4;
  const int q0 = qb * 64;
  const int tid = threadIdx.x, l = tid & 63, w = tid >> 6;

  __shared__ __attribute__((aligned(16))) char kbuf[2][16384];
  __shared__ float rbuf[4][64];

  const char* Qrow = (const char*)(Qb + (size_t)bh * 131072ull);
  const char* Krow = (const char*)(Kb + (size_t)bh * 131072ull);

  // Q fragments straight from global (L2/L3-resident)
  short8 aq[4][2];
#pragma unroll
  for (int qf = 0; qf < 4; ++qf)
#pragma unroll
    for (int kk = 0; kk < 2; ++kk)
      aq[qf][kk] = *(const short8*)(Qrow + (size_t)(q0 + qf * 16 + (l & 15)) * 128 +
                                    kk * 64 + (l >> 4) * 16);
  // per-qf mask row pointers (word column fixed = w)
  const u32* mbase[4];
#pragma unroll
  for (int qf = 0; qf < 4; ++qf)
    mbase[qf] = mbits + (size_t)(b * 2048 + q0 + qf * 16 + (l & 15)) * 64 + w;

  // prologue: stage K(0), then (ordered) preload mask(0)
  ORDER_FENCE();
#pragma unroll
  for (int j = 0; j < 4; ++j) {
    const int row = j * 32 + w * 8 + (l >> 3);
    GLDS16(Krow + (size_t)row * 128 + (((l & 7) * 16) ^ ((row & 7) << 4)),
           kbuf[0] + j * 4096 + w * 1024);
  }
  ORDER_FENCE();
  u32 mreg[4];
#pragma unroll
  for (int qf = 0; qf < 4; ++qf) mreg[qf] = mbase[qf][0];

  float lsum[4] = {0.f, 0.f, 0.f, 0.f};
  for (int t = 0; t < 16; ++t) {
    // own K(t) staging retired (mask loads, newer, may stay in flight),
    // then barrier so ALL threads' staging is visible (t=0 included!)
    asm volatile("s_waitcnt vmcnt(4) lgkmcnt(0)" ::: "memory");
    __builtin_amdgcn_s_barrier();
    u32 mnext[4] = {0, 0, 0, 0};
    if (t < 15) {
      ORDER_FENCE();
#pragma unroll
      for (int j = 0; j < 4; ++j) {
        const int row = j * 32 + w * 8 + (l >> 3);
        GLDS16(Krow + (size_t)((t + 1) * 128 + row) * 128 + (((l & 7) * 16) ^ ((row & 7) << 4)),
               kbuf[(t + 1) & 1] + j * 4096 + w * 1024);
      }
      ORDER_FENCE();
#pragma unroll
      for (int qf = 0; qf < 4; ++qf) mnext[qf] = mbase[qf][(t + 1) * 4];
    }
#pragma unroll
    for (int i = 0; i < 2; ++i) {
      const int krow = (w * 2 + i) * 16 + (l & 15);
      short8 ak[2];
#pragma unroll
      for (int kk = 0; kk < 2; ++kk)
        ak[kk] = *(const short8*)(kbuf[t & 1] + krow * 128 +
                                  ((kk * 64 + (l >> 4) * 16) ^ ((krow & 7) << 4)));
#pragma unroll
      for (int qf = 0; qf < 4; ++qf) {
        f32x4 sc = {0.f, 0.f, 0.f, 0.f};
        sc = __builtin_amdgcn_mfma_f32_16x16x32_bf16(ak[0], aq[qf][0], sc, 0, 0, 0);
        sc = __builtin_amdgcn_mfma_f32_16x16x32_bf16(ak[1], aq[qf][1], sc, 0, 0, 0);
        const int bp = i * 16 + (l >> 4) * 4;
        float s = 0.f;
#pragma unroll
        for (int r = 0; r < 4; ++r)
          s += ((mreg[qf] >> (bp + r)) & 1u) ? 0.f : EXP2(sc[r]);
        lsum[qf] += s;
      }
    }
#pragma unroll
    for (int qf = 0; qf < 4; ++qf) mreg[qf] = mnext[qf];
  }
#pragma unroll
  for (int qf = 0; qf < 4; ++qf) {
    float v = lsum[qf];
    v += __shfl_xor(v, 16);
    v += __shfl_xor(v, 32);
    if (l < 16) rbuf[w][qf * 16 + l] = v;
  }
  __syncthreads();
  if (tid < 64)
    lrow[(size_t)bh * 2048 + q0 + tid] =
        rbuf[0][tid] + rbuf[1][tid] + rbuf[2][tid] + rbuf[3][tid];
}

// ---------- single-pass fused attention, single-barrier deferred-PV pipeline ----
// QBLK=128, BK=64 (32 tiles), 512 threads. Per tile: one barrier; stores+PV of
// tile t-1 run after it (P double-buffered, V triple-buffered).
// Grid flattened to 512 with XCD swizzle: 4 consecutive bh per XCD (K/V L2-local).
__global__ __launch_bounds__(512, 4) void attn_kernel(
    const u16* __restrict__ Qb, const u16* __restrict__ Kb,
    const u16* __restrict__ Vt, const u32* __restrict__ mbits,
    const float* __restrict__ lrow, float* __restrict__ attn,
    u16* __restrict__ preWo)
{
  const int lid = blockIdx.x;
  const int swz = (lid & 7) * 64 + (lid >> 3);   // bijective (512 % 8 == 0)
  const int bh = swz >> 4, qb = swz & 15;
  const int b = bh >> 4, h = bh & 15;
  const int q0 = qb * 128;
  const int tid = threadIdx.x, l = tid & 63, w = tid >> 6;
  const int wk = w & 3, wqh = w >> 2;   // QK phase: k-frag, q-half
  const int wq = w >> 1, wd = w & 1;    // PV phase: q-quarter, d-half

  __shared__ __attribute__((aligned(16))) char kbuf[2][8192];
  __shared__ __attribute__((aligned(16))) char vbuf[3][8192];
  __shared__ __attribute__((aligned(16))) char Psm[2][16384];  // P bf16 [128][64] x2

  const char* Qrow = (const char*)(Qb + (size_t)bh * 131072ull);
  const char* Krow = (const char*)(Kb + (size_t)bh * 131072ull);
  const char* Vrow = (const char*)(Vt + (size_t)bh * 131072ull);

  // prologue: stage Q (into Psm[0] temporarily), K(0), V(0)
  {
    const int row = tid >> 3, byte = (tid & 7) * 16;
    GLDS16(Qrow + (size_t)(q0 + row) * 128 + (byte ^ ((row & 7) << 4)), Psm[0] + w * 1024);
    const int row2 = 64 + row;
    GLDS16(Qrow + (size_t)(q0 + row2) * 128 + (byte ^ ((row2 & 7) << 4)), Psm[0] + 8192 + w * 1024);
    GLDS16(Krow + (size_t)row * 128 + (byte ^ ((row & 7) << 4)), kbuf[0] + w * 1024);
    GLDS16(Vrow + (size_t)row * 4096 + (byte ^ ((row & 7) << 4)), vbuf[0] + w * 1024);
  }
  __syncthreads();
  short8 aq[4][2];
#pragma unroll
  for (int qf = 0; qf < 4; ++qf)
#pragma unroll
    for (int kk = 0; kk < 2; ++kk) {
      const int row = wqh * 64 + qf * 16 + (l & 15);
      aq[qf][kk] = *(const short8*)(Psm[0] + row * 128 +
                                    ((kk * 64 + (l >> 4) * 16) ^ ((row & 7) << 4)));
    }
  float il[4];
#pragma unroll
  for (int qf = 0; qf < 4; ++qf) {
    const float lv = lrow[(size_t)bh * 2048 + q0 + wqh * 64 + qf * 16 + (l & 15)];
    il[qf] = (lv > 0.f) ? 1.0f / lv : 0.f;
  }
  __syncthreads();   // Q frag reads done; Psm[0] free for P(0)

  // per-qf mask row pointers (word column fixed = wk>>1)
  const u32* mbase[4];
#pragma unroll
  for (int qf = 0; qf < 4; ++qf)
    mbase[qf] = mbits + (size_t)(b * 2048 + q0 + wqh * 64 + qf * 16 + (l & 15)) * 64 + (wk >> 1);
  u32 mreg[4];
#pragma unroll
  for (int qf = 0; qf < 4; ++qf) mreg[qf] = mbase[qf][0];

  f32x4 oacc[2][2] = {};
  const int kbit = (wk & 1) * 16 + (l >> 4) * 4;
  int vstage = 1, vprev = 2;   // (t+1)%3 and (t-1)%3 ring indices
  for (int t = 0; t < 32; ++t) {
    // single barrier per tile: staging(t) visible + P(t-1) visible.
    // vmcnt: in-order retirement; ops newer than staging(t) = 4 mask (+4 stores
    // once t>=2) -> vmcnt(4) at t==1, vmcnt(8) after. t==0 covered by prologue.
    if (t == 1) {
      asm volatile("s_waitcnt vmcnt(4) lgkmcnt(0)" ::: "memory");
      __builtin_amdgcn_s_barrier();
    } else if (t >= 2) {
      asm volatile("s_waitcnt vmcnt(8) lgkmcnt(0)" ::: "memory");
      __builtin_amdgcn_s_barrier();
    }
    u32 mnext[4] = {0, 0, 0, 0};
    if (t < 31) {
      const int row = tid >> 3, byte = (tid & 7) * 16;
      ORDER_FENCE();
      GLDS16(Krow + (size_t)((t + 1) * 64 + row) * 128 + (byte ^ ((row & 7) << 4)),
             kbuf[(t + 1) & 1] + w * 1024);
      GLDS16(Vrow + (size_t)row * 4096 + (t + 1) * 128 + (byte ^ ((row & 7) << 4)),
             vbuf[vstage] + w * 1024);
      ORDER_FENCE();
#pragma unroll
      for (int qf = 0; qf < 4; ++qf) mnext[qf] = mbase[qf][(t + 1) * 2];
      ORDER_FENCE();
    }
    // deferred attn stores for tile t-1 (coalesced 256B readback from Psm)
    if (t > 0) {
      const char* Pp = Psm[(t - 1) & 1];
#pragma unroll
      for (int it = 0; it < 4; ++it) {
        const int q = w * 16 + it * 4 + (l >> 4);
        const uint2 pv = *(const uint2*)(Pp + q * 128 + (((l & 15) * 8) ^ ((q & 7) << 4)));
        f32x4 o;
        o[0] = __uint_as_float(pv.x << 16);
        o[1] = __uint_as_float(pv.x & 0xffff0000u);
        o[2] = __uint_as_float(pv.y << 16);
        o[3] = __uint_as_float(pv.y & 0xffff0000u);
        __builtin_nontemporal_store(o, (f32x4*)(attn +
            ((size_t)bh * 2048 + q0 + q) * 2048 + (t - 1) * 64 + (l & 15) * 4));
      }
    }
    // QK(t) (swapped operands): sc rows = k-local, cols = q-local
    short8 ak[2];
    {
      const int krow = wk * 16 + (l & 15);
      ak[0] = *(const short8*)(kbuf[t & 1] + krow * 128 +
                               (((l >> 4) * 16) ^ ((krow & 7) << 4)));
      ak[1] = *(const short8*)(kbuf[t & 1] + krow * 128 +
                               ((64 + (l >> 4) * 16) ^ ((krow & 7) << 4)));
    }
#pragma unroll
    for (int qf = 0; qf < 4; ++qf) {
      f32x4 sc = {0.f, 0.f, 0.f, 0.f};
      sc = __builtin_amdgcn_mfma_f32_16x16x32_bf16(ak[0], aq[qf][0], sc, 0, 0, 0);
      sc = __builtin_amdgcn_mfma_f32_16x16x32_bf16(ak[1], aq[qf][1], sc, 0, 0, 0);
      const int q = wqh * 64 + qf * 16 + (l & 15);
      float p[4];
#pragma unroll
      for (int r = 0; r < 4; ++r)
        p[r] = ((mreg[qf] >> (kbit + r)) & 1u) ? 0.f : EXP2(sc[r]) * il[qf];
      uint2 pk;
      pk.x = (u32)f2bf(p[0]) | ((u32)f2bf(p[1]) << 16);
      pk.y = (u32)f2bf(p[2]) | ((u32)f2bf(p[3]) << 16);
      *(uint2*)(Psm[t & 1] + q * 128 + ((wk * 32 + (l >> 4) * 8) ^ ((q & 7) << 4))) = pk;
    }
#pragma unroll
    for (int qf = 0; qf < 4; ++qf) mreg[qf] = mnext[qf];
    // PV(t-1): oacc += P(t-1) x V(t-1)
    if (t > 0) {
      const char* Pp = Psm[(t - 1) & 1];
#pragma unroll
      for (int ka = 0; ka < 2; ++ka) {
        short8 pa[2], vb[2];
#pragma unroll
        for (int i = 0; i < 2; ++i) {
          const int qr = wq * 32 + i * 16 + (l & 15);
          pa[i] = *(const short8*)(Pp + qr * 128 +
                                   ((ka * 64 + (l >> 4) * 16) ^ ((qr & 7) << 4)));
        }
#pragma unroll
        for (int j = 0; j < 2; ++j) {
          const int dr = wd * 32 + j * 16 + (l & 15);
          vb[j] = *(const short8*)(vbuf[vprev] + dr * 128 +
                                   ((ka * 64 + (l >> 4) * 16) ^ ((dr & 7) << 4)));
        }
#pragma unroll
        for (int i = 0; i < 2; ++i)
#pragma unroll
          for (int j = 0; j < 2; ++j)
            oacc[i][j] = __builtin_amdgcn_mfma_f32_16x16x32_bf16(pa[i], vb[j], oacc[i][j], 0, 0, 0);
      }
    }
    vstage = (vstage == 2) ? 0 : vstage + 1;
    vprev = (vprev == 2) ? 0 : vprev + 1;
  }

  // tail: stores(31) + PV(31); V(31) lives in vbuf[31 % 3 = 1]
  asm volatile("s_waitcnt lgkmcnt(0)" ::: "memory");
  __builtin_amdgcn_s_barrier();
  {
    const char* Pp = Psm[1];
#pragma unroll
    for (int it = 0; it < 4; ++it) {
      const int q = w * 16 + it * 4 + (l >> 4);
      const uint2 pv = *(const uint2*)(Pp + q * 128 + (((l & 15) * 8) ^ ((q & 7) << 4)));
      f32x4 o;
      o[0] = __uint_as_float(pv.x << 16);
      o[1] = __uint_as_float(pv.x & 0xffff0000u);
      o[2] = __uint_as_float(pv.y << 16);
      o[3] = __uint_as_float(pv.y & 0xffff0000u);
      __builtin_nontemporal_store(o, (f32x4*)(attn +
          ((size_t)bh * 2048 + q0 + q) * 2048 + 31 * 64 + (l & 15) * 4));
    }
#pragma unroll
    for (int ka = 0; ka < 2; ++ka) {
      short8 pa[2], vb[2];
#pragma unroll
      for (int i = 0; i < 2; ++i) {
        const int qr = wq * 32 + i * 16 + (l & 15);
        pa[i] = *(const short8*)(Pp + qr * 128 +
                                 ((ka * 64 + (l >> 4) * 16) ^ ((qr & 7) << 4)));
      }
#pragma unroll
      for (int j = 0; j < 2; ++j) {
        const int dr = wd * 32 + j * 16 + (l & 15);
        vb[j] = *(const short8*)(vbuf[1] + dr * 128 +
                                 ((ka * 64 + (l >> 4) * 16) ^ ((dr & 7) << 4)));
      }
#pragma unroll
      for (int i = 0; i < 2; ++i)
#pragma unroll
        for (int j = 0; j < 2; ++j)
          oacc[i][j] = __builtin_amdgcn_mfma_f32_16x16x32_bf16(pa[i], vb[j], oacc[i][j], 0, 0, 0);
    }
  }

  // epilogue: O (already normalized) scattered into the buggy-reshape layout
#pragma unroll
  for (int i = 0; i < 2; ++i)
#pragma unroll
    for (int j = 0; j < 2; ++j)
#pragma unroll
      for (int r = 0; r < 4; ++r) {
        const int qg = q0 + wq * 32 + i * 16 + (l >> 4) * 4 + r;
        const int dd = wd * 32 + j * 16 + (l & 15);
        const size_t off = (size_t)b * 2097152ull +
                           ((size_t)((h >> 1) * 256 + (qg >> 3))) * 1024ull +
                           (size_t)((qg & 7) * 128 + (h & 1) * 64 + dd);
        preWo[off] = f2bf(oacc[i][j][r]);
      }
}

// ---------- output projection GEMM: 128x64 tiles, 1D grid (512), XCD swizzle ----
__global__ __launch_bounds__(256, 2) void gemm_out_kernel(
    const u16* __restrict__ A0, const u16* __restrict__ B0,
    const float* __restrict__ bias, float* __restrict__ out)
{
  const char* A = (const char*)A0;
  const char* B = (const char*)B0;
  const int lid = blockIdx.x;
  const int g = (lid & 7) * 64 + (lid >> 3);   // bijective, 512 % 8 == 0
  const int m0 = (g >> 4) * 128, n0 = (g & 15) * 64;
  const int tid = threadIdx.x, l = tid & 63, w = tid >> 6;
  const int wm = w >> 1, wn = w & 1;
  __shared__ __attribute__((aligned(16))) char SM[24576];
  char* Asm = SM;
  char* Bsm = SM + 16384;
  f32x4 acc[4][2] = {};
  for (int kt = 0; kt < 16; ++kt) {
#pragma unroll
    for (int j = 0; j < 4; ++j) {
      const int rt = w * 32 + j * 8 + (l >> 3);
      const int swk = ((l & 7) * 16) ^ ((rt & 7) << 4);
      GLDS16(A + (size_t)(m0 + rt) * 2048 + kt * 128 + swk, Asm + (w * 32 + j * 8) * 128);
    }
#pragma unroll
    for (int j = 0; j < 2; ++j) {
      const int rt = w * 16 + j * 8 + (l >> 3);
      const int swk = ((l & 7) * 16) ^ ((rt & 7) << 4);
      GLDS16(B + (size_t)(n0 + rt) * 2048 + kt * 128 + swk, Bsm + (w * 16 + j * 8) * 128);
    }
    __syncthreads();
#pragma unroll
    for (int kk = 0; kk < 2; ++kk) {
      short8 af[4], bfr[2];
#pragma unroll
      for (int mf = 0; mf < 4; ++mf) {
        const int row = wm * 64 + mf * 16 + (l & 15);
        const int kb = kk * 64 + (l >> 4) * 16;
        af[mf] = *(const short8*)(Asm + row * 128 + (kb ^ ((row & 7) << 4)));
      }
#pragma unroll
      for (int fc = 0; fc < 2; ++fc) {
        const int row = wn * 32 + fc * 16 + (l & 15);
        const int kb = kk * 64 + (l >> 4) * 16;
        bfr[fc] = *(const short8*)(Bsm + row * 128 + (kb ^ ((row & 7) << 4)));
      }
#pragma unroll
      for (int mf = 0; mf < 4; ++mf)
#pragma unroll
        for (int fc = 0; fc < 2; ++fc)
          acc[mf][fc] = __builtin_amdgcn_mfma_f32_16x16x32_bf16(af[mf], bfr[fc], acc[mf][fc], 0, 0, 0);
    }
    __syncthreads();
  }
#pragma unroll
  for (int mf = 0; mf < 4; ++mf)
#pragma unroll
    for (int fc = 0; fc < 2; ++fc)
#pragma unroll
      for (int r = 0; r < 4; ++r) {
        const int m = m0 + wm * 64 + mf * 16 + (l >> 4) * 4 + r;
        const int n = n0 + wn * 32 + fc * 16 + (l & 15);
        out[(size_t)m * 1024 + n] = acc[mf][fc][r] + bias[n];
      }
}

extern "C" void kernel_launch(void* const* d_in, const int* in_sizes, int n_in,
                              void* d_out, int out_size, void* d_ws, size_t ws_size,
                              hipStream_t stream) {
  const float* q  = (const float*)d_in[0];
  const float* k  = (const float*)d_in[1];
  const float* v  = (const float*)d_in[2];
  const int*  mask = (const int*)d_in[3];
  const float* Wq = (const float*)d_in[5];
  const float* bq = (const float*)d_in[6];
  const float* Wk = (const float*)d_in[7];
  const float* bk = (const float*)d_in[8];
  const float* Wv = (const float*)d_in[9];
  const float* bv = (const float*)d_in[10];
  const float* Wo = (const float*)d_in[11];
  const float* bo = (const float*)d_in[12];

  float* out0 = (float*)d_out;
  float* attn = out0 + 4194304;            // [32][2048][2048] fp32
  u16* X = (u16*)attn;                     // bf16 q,k,v staging lives in the attn
                                           // region until attn_kernel overwrites it
  char* ws = (char*)d_ws;
  u16* Qb    = (u16*)(ws);                 // [32][2048][64] bf16
  u16* Kb    = (u16*)(ws + 8388608);
  u16* Vt    = (u16*)(ws + 16777216);      // [32][64][2048] bf16
  u16* preWo = (u16*)(ws + 25165824);      // [4096][1024] bf16 (scrambled layout)
  u16* Wb    = (u16*)(ws + 33554432);      // Wq,Wk,Wv,Wo bf16
  u32* mbits = (u32*)(ws + 41943040);      // [2][2048][64] bit-packed mask
  // lrow reuses the Wq-bf16 slot (Wq only needed by gemm_qkv, which runs earlier)
  float* lrow = (float*)(ws + 33554432);   // [32][2048] fp32

  prep_kernel<<<dim3(1024), 256, 0, stream>>>(q, k, v, mask, Wq, Wk, Wv, Wo,
                                              X, Wb, (u64*)mbits);
  gemm_qkv_kernel<<<dim3(768), 256, 0, stream>>>(X, Wb, bq, bk, bv, Qb, Kb, Vt);
  lsum_kernel<<<dim3(1024), 256, 0, stream>>>(Qb, Kb, mbits, lrow);
  attn_kernel<<<dim3(512), 512, 0, stream>>>(Qb, Kb, Vt, mbits, lrow, attn, preWo);
  gemm_out_kernel<<<dim3(512), 256, 0, stream>>>(preWo, Wb + 3u * 1048576u, bo, out0);
}